// Round 12
// baseline (274.791 us; speedup 1.0000x reference)
//
#include <hip/hip_runtime.h>
#include <hip/hip_bf16.h>
#include <cstdint>

typedef unsigned short u16;
typedef __bf16 bf16x8 __attribute__((ext_vector_type(8)));
typedef float f32x4 __attribute__((ext_vector_type(4)));
typedef int i32x4 __attribute__((ext_vector_type(4)));

#define SEQ 1024
#define HID 4096
#define NHQ 32
#define NKVH 8
#define HDIM 128
#define NB 2
#define NROWS (NB*SEQ)

static __device__ __forceinline__ u16 f2bf(float x) {
  __hip_bfloat16 h = __float2bfloat16(x);
  return *reinterpret_cast<u16*>(&h);
}

static __device__ __forceinline__ void gload16(const void* g, void* l) {
  __builtin_amdgcn_global_load_lds((__attribute__((address_space(1))) void*)(void*)g,
                                   (__attribute__((address_space(3))) void*)l, 16, 0, 0);
}

static __device__ __forceinline__ int pack4i8(float a, float b, float c, float d,
                                              float s, float lo, float hi) {
  int x0 = (int)fminf(fmaxf(rintf(a*s), lo), hi);
  int x1 = (int)fminf(fmaxf(rintf(b*s), lo), hi);
  int x2 = (int)fminf(fmaxf(rintf(c*s), lo), hi);
  int x3 = (int)fminf(fmaxf(rintf(d*s), lo), hi);
  return (x0 & 255) | ((x1 & 255) << 8) | ((x2 & 255) << 16) | ((x3 & 255) << 24);
}

// ---------------- pass 1 (merged): weight abs-sums (bx<2560) + act quant (bx>=2560) ----------------
__global__ __launch_bounds__(256) void k_pass1(const float* __restrict__ wq_, const float* __restrict__ wk_,
                                               const float* __restrict__ wv_, const float* __restrict__ wo_,
                                               float* __restrict__ partial,
                                               const float* __restrict__ x, char* __restrict__ xq,
                                               float* __restrict__ xs) {
  __shared__ float red[4];
  int bx = blockIdx.x;
  if (bx < 2560) {
    const float* w; long n4; int pbase, lb, nb;
    if (bx < 1024)      { w = wq_; n4 = 4194304; pbase = 0;    lb = bx;        nb = 1024; }
    else if (bx < 1280) { w = wk_; n4 = 1048576; pbase = 1024; lb = bx - 1024; nb = 256; }
    else if (bx < 1536) { w = wv_; n4 = 1048576; pbase = 1280; lb = bx - 1280; nb = 256; }
    else                { w = wo_; n4 = 4194304; pbase = 1536; lb = bx - 1536; nb = 1024; }
    float s = 0.f;
    long stride = (long)nb * 256;
    const float4* w4 = (const float4*)w;
    for (long j = (long)lb*256 + threadIdx.x; j < n4; j += stride) {
      float4 v = w4[j];
      s += fabsf(v.x) + fabsf(v.y) + fabsf(v.z) + fabsf(v.w);
    }
    #pragma unroll
    for (int off = 1; off < 64; off <<= 1) s += __shfl_xor(s, off);
    if ((threadIdx.x & 63) == 0) red[threadIdx.x >> 6] = s;
    __syncthreads();
    if (threadIdx.x == 0) partial[pbase + lb] = red[0] + red[1] + red[2] + red[3];
  } else {
    long row = bx - 2560;
    const float4* xr = (const float4*)(x + row*HID);
    float4 v[4];
    float am = 0.f;
    #pragma unroll
    for (int j = 0; j < 4; ++j) {
      v[j] = xr[j*256 + threadIdx.x];
      am = fmaxf(am, fmaxf(fmaxf(fabsf(v[j].x), fabsf(v[j].y)), fmaxf(fabsf(v[j].z), fabsf(v[j].w))));
    }
    #pragma unroll
    for (int off = 1; off < 64; off <<= 1) am = fmaxf(am, __shfl_xor(am, off));
    if ((threadIdx.x & 63) == 0) red[threadIdx.x >> 6] = am;
    __syncthreads();
    am = fmaxf(fmaxf(red[0], red[1]), fmaxf(red[2], red[3]));
    float amc = fmaxf(am, 1e-5f);
    float s = 127.0f / amc;
    int* oq = (int*)(xq + row*HID);
    #pragma unroll
    for (int j = 0; j < 4; ++j)
      oq[j*256 + threadIdx.x] = pack4i8(v[j].x, v[j].y, v[j].z, v[j].w, s, -128.f, 127.f);
    if (threadIdx.x == 0) xs[row] = amc / 127.0f;
  }
}

// ---------------- weight scales (pass 2) ----------------
__global__ __launch_bounds__(256) void k_wscale(const float* __restrict__ partial,
                                                float* __restrict__ wsc) {
  __shared__ float red[4];
  const float nelem[4] = {16777216.f, 4194304.f, 4194304.f, 16777216.f};
  const int pbase[4] = {0, 1024, 1280, 1536};
  const int pcnt[4]  = {1024, 256, 256, 1024};
  for (int wi = 0; wi < 4; ++wi) {
    float s = 0.f;
    for (int j = threadIdx.x; j < pcnt[wi]; j += 256) s += partial[pbase[wi] + j];
    #pragma unroll
    for (int off = 1; off < 64; off <<= 1) s += __shfl_xor(s, off);
    if ((threadIdx.x & 63) == 0) red[threadIdx.x >> 6] = s;
    __syncthreads();
    if (threadIdx.x == 0) wsc[wi] = fmaxf((red[0]+red[1]+red[2]+red[3]) / nelem[wi], 1e-5f);
    __syncthreads();
  }
}

// ---------------- merged ternary weight quantize -> int8 + rope tables (41216 blocks) ----------------
__global__ __launch_bounds__(256) void k_quantw8_all(const float* __restrict__ wq_, const float* __restrict__ wk_,
                                                     const float* __restrict__ wv_, const float* __restrict__ wo_,
                                                     char* __restrict__ oq_, char* __restrict__ ok_,
                                                     char* __restrict__ ov_, char* __restrict__ oo_,
                                                     const float* __restrict__ wsc,
                                                     float* __restrict__ cosb, float* __restrict__ sinb) {
  int bx = blockIdx.x;
  if (bx >= 40960) {
    int idx = (bx - 40960)*256 + threadIdx.x;     // 1024*64
    int s = idx >> 6, i = idx & 63;
    float e = (2.0f * (float)i) / 128.0f;
    float inv = 1.0f / powf(500000.0f, e);
    float f = (float)s * inv;
    cosb[idx] = cosf(f);
    sinb[idx] = sinf(f);
    return;
  }
  const float* src; char* dst; int idx; long base;
  if (bx < 16384)      { src = wq_; dst = oq_; idx = 0; base = bx; }
  else if (bx < 20480) { src = wk_; dst = ok_; idx = 1; base = bx - 16384; }
  else if (bx < 24576) { src = wv_; dst = ov_; idx = 2; base = bx - 20480; }
  else                 { src = wo_; dst = oo_; idx = 3; base = bx - 24576; }
  long j = base*256 + threadIdx.x;        // float4 index; 1024 per weight row
  long oj = j;
  if (idx <= 1) {
    long row = j >> 10;
    int u = (int)(row & 31);
    long prow = (row & ~31L) | (long)((u >> 1) | ((u & 1) << 4));
    oj = (prow << 10) | (j & 1023);
  }
  float inv = 1.0f / wsc[idx];
  float4 v = ((const float4*)src)[j];
  ((int*)dst)[oj] = pack4i8(v.x, v.y, v.z, v.w, inv, -1.f, 1.f);
}

// ---------------- i8 O-GEMM: 128x128 tile, 2 waves (64x128 each), 1 barrier/step ----------------
// Counted-vmcnt pipeline over a UNIFORM global_load_lds stream (FIFO-safe, m135/m218).
__global__ __launch_bounds__(128, 2) void k_gemm8(const char* __restrict__ A, const char* __restrict__ W,
                                                  float* __restrict__ C, const float* __restrict__ arow,
                                                  const float* __restrict__ wsc, int widx,
                                                  int M, int N, int K) {
  __shared__ char As[3][128*64] __attribute__((aligned(16)));
  __shared__ char Ws_[3][128*64] __attribute__((aligned(16)));
  int t = threadIdx.x;
  int bid = blockIdx.x;
  int xcd = bid & 7, w = bid >> 3;                 // w in 0..63
  int bm = ((xcd & 1) << 3) + (w >> 3);            // 0..15
  int bn = ((xcd >> 1) << 3) + (w & 7);            // 0..31
  const char* Ab = A + (long)bm*128*K;
  const char* Wb = W + (long)bn*128*K;
  int lane = t & 63, wid = t >> 6;
  int lrow = lane & 15, l8 = lane >> 4;
  int ch0 = (l8 ^ ((lrow >> 1) & 3)) * 16;
  i32x4 zero = {0, 0, 0, 0};
  i32x4 acc[4][8];
  #pragma unroll
  for (int mi = 0; mi < 4; ++mi)
    #pragma unroll
    for (int ni = 0; ni < 8; ++ni) acc[mi][ni] = zero;

  auto stage = [&](int buf, int kt) {              // 8 VMEM ops per thread (all gload_lds)
    #pragma unroll
    for (int i = 0; i < 4; ++i) {
      int c = t + 128*i;
      int row = c >> 2;
      int ci = ((c & 3) ^ ((row >> 1) & 3)) * 16;  // pre-swizzled global chunk (rule #21)
      gload16(Ab + (long)row*K + kt*64 + ci, &As[buf][c*16]);
      gload16(Wb + (long)row*K + kt*64 + ci, &Ws_[buf][c*16]);
    }
  };

  int nk = K >> 6;                                 // 64
  stage(0, 0); stage(1, 1);
  asm volatile("s_waitcnt vmcnt(8)" ::: "memory");
  __builtin_amdgcn_sched_barrier(0);
  __builtin_amdgcn_s_barrier();
  __builtin_amdgcn_sched_barrier(0);
  for (int kt = 0; kt < nk; ++kt) {
    int cur = kt % 3;
    i32x4 af[4], bfr[8];
    #pragma unroll
    for (int mi = 0; mi < 4; ++mi) af[mi] = *(const i32x4*)&As[cur][(wid*64 + mi*16 + lrow)*64 + ch0];
    #pragma unroll
    for (int ni = 0; ni < 8; ++ni) bfr[ni] = *(const i32x4*)&Ws_[cur][(ni*16 + lrow)*64 + ch0];
    if (kt + 2 < nk) stage((kt + 2) % 3, kt + 2);
    __builtin_amdgcn_s_setprio(1);
    #pragma unroll
    for (int mi = 0; mi < 4; ++mi)
      #pragma unroll
      for (int ni = 0; ni < 8; ++ni)
        acc[mi][ni] = __builtin_amdgcn_mfma_i32_16x16x64_i8(af[mi], bfr[ni], acc[mi][ni], 0, 0, 0);
    __builtin_amdgcn_s_setprio(0);
    if (kt + 2 < nk)      asm volatile("s_waitcnt vmcnt(8)" ::: "memory");
    else if (kt + 1 < nk) asm volatile("s_waitcnt vmcnt(0)" ::: "memory");
    if (kt + 1 < nk) {
      __builtin_amdgcn_sched_barrier(0);
      __builtin_amdgcn_s_barrier();
      __builtin_amdgcn_sched_barrier(0);
    }
  }
  float ws = wsc[widx];
  #pragma unroll
  for (int mi = 0; mi < 4; ++mi)
    #pragma unroll
    for (int r = 0; r < 4; ++r) {
      int row = bm*128 + wid*64 + mi*16 + l8*4 + r;
      float sc = arow[row] * ws;
      #pragma unroll
      for (int ni = 0; ni < 8; ++ni) {
        int col = bn*128 + ni*16 + lrow;
        C[(long)row*N + col] = (float)acc[mi][ni][r] * sc;
      }
    }
}

// ---------------- merged i8 QKV GEMM: 128x128, 2 waves, 1 barrier/step, fused RoPE ----------------
__global__ __launch_bounds__(128, 2) void k_gemm8_qkv(const char* __restrict__ A,
    const char* __restrict__ Wq, const char* __restrict__ Wk, const char* __restrict__ Wv,
    u16* __restrict__ Qb, u16* __restrict__ Kb, u16* __restrict__ Vt,
    const float* __restrict__ arow, const float* __restrict__ wsc,
    const float* __restrict__ cosb, const float* __restrict__ sinb) {
  const int K = 4096;
  int bid = blockIdx.x;
  int xcd = bid & 7, w = bid >> 3;                 // w in 0..95
  int kind, bm, bn;
  const char* W;
  if (w < 64)      { kind = 0; bm = ((xcd & 1) << 3) + (w >> 3); bn = ((xcd >> 1) << 3) + (w & 7); W = Wq; }
  else if (w < 80) { int u = w - 64; kind = 1; bm = (xcd << 1) + (u >> 3); bn = u & 7; W = Wk; }
  else             { int u = w - 80; kind = 2; bm = (xcd << 1) + (u >> 3); bn = u & 7; W = Wv; }

  __shared__ char As[3][128*64] __attribute__((aligned(16)));
  __shared__ char Ws_[3][128*64] __attribute__((aligned(16)));
  int t = threadIdx.x;
  const char* Ab = A + (long)bm*128*K;
  const char* Wb = W + (long)bn*128*K;
  int lane = t & 63, wid = t >> 6;
  int lrow = lane & 15, l8 = lane >> 4;
  int ch0 = (l8 ^ ((lrow >> 1) & 3)) * 16;
  i32x4 zero = {0, 0, 0, 0};
  i32x4 acc[4][8];
  #pragma unroll
  for (int mi = 0; mi < 4; ++mi)
    #pragma unroll
    for (int ni = 0; ni < 8; ++ni) acc[mi][ni] = zero;

  auto stage = [&](int buf, int kt) {              // 8 VMEM ops per thread (all gload_lds)
    #pragma unroll
    for (int i = 0; i < 4; ++i) {
      int c = t + 128*i;
      int row = c >> 2;
      int ci = ((c & 3) ^ ((row >> 1) & 3)) * 16;
      gload16(Ab + (long)row*K + kt*64 + ci, &As[buf][c*16]);
      gload16(Wb + (long)row*K + kt*64 + ci, &Ws_[buf][c*16]);
    }
  };

  int nk = K >> 6;                                 // 64
  stage(0, 0); stage(1, 1);
  asm volatile("s_waitcnt vmcnt(8)" ::: "memory");
  __builtin_amdgcn_sched_barrier(0);
  __builtin_amdgcn_s_barrier();
  __builtin_amdgcn_sched_barrier(0);
  for (int kt = 0; kt < nk; ++kt) {
    int cur = kt % 3;
    i32x4 af[4], bfr[8];
    #pragma unroll
    for (int mi = 0; mi < 4; ++mi) af[mi] = *(const i32x4*)&As[cur][(wid*64 + mi*16 + lrow)*64 + ch0];
    #pragma unroll
    for (int ni = 0; ni < 8; ++ni) bfr[ni] = *(const i32x4*)&Ws_[cur][(ni*16 + lrow)*64 + ch0];
    if (kt + 2 < nk) stage((kt + 2) % 3, kt + 2);
    __builtin_amdgcn_s_setprio(1);
    #pragma unroll
    for (int mi = 0; mi < 4; ++mi)
      #pragma unroll
      for (int ni = 0; ni < 8; ++ni)
        acc[mi][ni] = __builtin_amdgcn_mfma_i32_16x16x64_i8(af[mi], bfr[ni], acc[mi][ni], 0, 0, 0);
    __builtin_amdgcn_s_setprio(0);
    if (kt + 2 < nk)      asm volatile("s_waitcnt vmcnt(8)" ::: "memory");
    else if (kt + 1 < nk) asm volatile("s_waitcnt vmcnt(0)" ::: "memory");
    if (kt + 1 < nk) {
      __builtin_amdgcn_sched_barrier(0);
      __builtin_amdgcn_s_barrier();
      __builtin_amdgcn_sched_barrier(0);
    }
  }

  if (kind == 2) {
    float ws = wsc[2];
    #pragma unroll
    for (int mi = 0; mi < 4; ++mi) {
      int row0 = bm*128 + wid*64 + mi*16 + l8*4;
      int bidx = row0 >> 10, s0 = row0 & 1023;
      #pragma unroll
      for (int ni = 0; ni < 8; ++ni) {
        int col = bn*128 + ni*16 + lrow;
        int hkv = col >> 7, d = col & 127;
        ushort4 o4;
        o4.x = f2bf((float)acc[mi][ni][0] * arow[row0+0] * ws);
        o4.y = f2bf((float)acc[mi][ni][1] * arow[row0+1] * ws);
        o4.z = f2bf((float)acc[mi][ni][2] * arow[row0+2] * ws);
        o4.w = f2bf((float)acc[mi][ni][3] * arow[row0+3] * ws);
        *(ushort4*)&Vt[(((long)bidx*NKVH + hkv)*HDIM + d)*SEQ + s0] = o4;
      }
    }
  } else {
    // Weight rows permuted at quant: (acc[mi][2j], acc[mi][2j+1]) are the RoPE pair
    // (B+2*lrow, B+2*lrow+1), B = bn*128 + j*32 — lane-local, no shfl.
    float ws = wsc[kind];
    u16* dst = kind ? Kb : Qb;
    int nh = kind ? NKVH : NHQ;
    #pragma unroll
    for (int mi = 0; mi < 4; ++mi) {
      #pragma unroll
      for (int r = 0; r < 4; ++r) {
        int row = bm*128 + wid*64 + mi*16 + l8*4 + r;
        int bidx = row >> 10, s = row & 1023;
        float sc = arow[row] * ws;
        #pragma unroll
        for (int j = 0; j < 4; ++j) {
          float a  = (float)acc[mi][2*j][r] * sc;
          float b2 = (float)acc[mi][2*j+1][r] * sc;
          int B = bn*128 + j*32;
          int h = B >> 7;
          int d = (B & 127) + 2*lrow;
          int i = d >> 1;
          float cc = cosb[(s << 6) + i], sn = sinb[(s << 6) + i];
          ushort2 o2;
          o2.x = f2bf(a*cc - b2*sn);
          o2.y = f2bf(a*sn + b2*cc);
          *(ushort2*)&dst[(((long)bidx*nh + h)*SEQ + s)*HDIM + d] = o2;
        }
      }
    }
  }
}

// ---------------- causal GQA flash attention: 2 waves x 32 q-rows, K+V LDS dbuf, causal-paired ----------------
__global__ __launch_bounds__(128, 2) void k_attn(const u16* __restrict__ qb, const u16* __restrict__ kb,
                                                 const u16* __restrict__ vt, float* __restrict__ ao) {
  int p = blockIdx.x, h = blockIdx.y, b = blockIdx.z;
  int t = threadIdx.x, lane = t & 63, wid = t >> 6;   // wid in {0,1}
  int lrow = lane & 15, l8 = lane >> 4;
  int x7 = lrow & 7;

  __shared__ u16 Ks[2][64*128] __attribute__((aligned(16)));
  __shared__ u16 Vs[2][128*64] __attribute__((aligned(16)));
  __shared__ u16 Ps[2][32][72] __attribute__((aligned(16)));

  const u16* kp = kb + ((long)(b*NKVH + (h >> 2)))*SEQ*HDIM;
  const u16* vp = vt + ((long)(b*NKVH + (h >> 2)))*HDIM*SEQ;

  auto stageK = [&](int buf, int j) {
    const u16* src = kp + (long)j*64*HDIM;
    #pragma unroll
    for (int i = 0; i < 8; ++i) {
      int r0 = wid*32 + i*4;
      int row = r0 + (lane >> 4);
      int cg = (lane & 15) ^ (row & 7);
      gload16(src + (long)row*HDIM + cg*8, &Ks[buf][r0*HDIM]);
    }
  };
  auto stageV = [&](int buf, int j) {
    #pragma unroll
    for (int i = 0; i < 8; ++i) {
      int r0 = wid*64 + i*8;
      int row = r0 + (lane >> 3);
      int cg = (lane & 7) ^ (row & 7);
      gload16(vp + (long)row*SEQ + j*64 + cg*8, &Vs[buf][r0*64]);
    }
  };

  for (int phase = 0; phase < 2; ++phase) {
    int qt = phase ? (15 - p) : p;
    int q0 = qt*64 + wid*32;
    const u16* qp = qb + (((long)(b*NHQ + h))*SEQ + q0)*HDIM;
    bf16x8 qf[2][4];
    #pragma unroll
    for (int mi = 0; mi < 2; ++mi)
      #pragma unroll
      for (int ks = 0; ks < 4; ++ks)
        qf[mi][ks] = *(const bf16x8*)&qp[(mi*16 + lrow)*HDIM + ks*32 + l8*8];
    f32x4 zero = {0.f, 0.f, 0.f, 0.f};
    f32x4 o[2][8];
    #pragma unroll
    for (int mi = 0; mi < 2; ++mi)
      #pragma unroll
      for (int f = 0; f < 8; ++f) o[mi][f] = zero;
    float m[2][4], ll[2][4];
    #pragma unroll
    for (int mi = 0; mi < 2; ++mi)
      #pragma unroll
      for (int r = 0; r < 4; ++r) { m[mi][r] = -1e30f; ll[mi][r] = 0.f; }

    int nj = qt + 1;
    stageK(0, 0); stageV(0, 0);
    __syncthreads();
    int cur = 0;
    for (int j = 0; j < nj; ++j) {
      if (j + 1 < nj) { stageK(cur ^ 1, j + 1); stageV(cur ^ 1, j + 1); }
      const u16* Kc = Ks[cur];
      const u16* Vc = Vs[cur];
      f32x4 sc4[2][4];
      #pragma unroll
      for (int mi = 0; mi < 2; ++mi)
        #pragma unroll
        for (int ni = 0; ni < 4; ++ni) sc4[mi][ni] = zero;
      __builtin_amdgcn_s_setprio(1);
      #pragma unroll
      for (int ni = 0; ni < 4; ++ni) {
        int row = ni*16 + lrow;
        #pragma unroll
        for (int ks = 0; ks < 4; ++ks) {
          int cl = (ks*4 + l8) ^ x7;
          bf16x8 kfr = *(const bf16x8*)&Kc[row*HDIM + cl*8];
          sc4[0][ni] = __builtin_amdgcn_mfma_f32_16x16x32_bf16(qf[0][ks], kfr, sc4[0][ni], 0, 0, 0);
          sc4[1][ni] = __builtin_amdgcn_mfma_f32_16x16x32_bf16(qf[1][ks], kfr, sc4[1][ni], 0, 0, 0);
        }
      }
      __builtin_amdgcn_s_setprio(0);
      const float scale = 0.08838834764831845f;
      float pm[2][4], pvv[2][4][4];
      bool diag = (j == qt);
      #pragma unroll
      for (int mi = 0; mi < 2; ++mi) {
        #pragma unroll
        for (int r = 0; r < 4; ++r) pm[mi][r] = -1e30f;
        #pragma unroll
        for (int ni = 0; ni < 4; ++ni) {
          int kv = j*64 + ni*16 + lrow;
          #pragma unroll
          for (int r = 0; r < 4; ++r) {
            int qr = q0 + mi*16 + l8*4 + r;
            float val = sc4[mi][ni][r] * scale;
            if (diag && kv > qr) val = -1e30f;
            pvv[mi][ni][r] = val;
            pm[mi][r] = fmaxf(pm[mi][r], val);
          }
        }
      }
      float fr[2][4];
      #pragma unroll
      for (int mi = 0; mi < 2; ++mi) {
        #pragma unroll
        for (int r = 0; r < 4; ++r) {
          #pragma unroll
          for (int off = 1; off < 16; off <<= 1) pm[mi][r] = fmaxf(pm[mi][r], __shfl_xor(pm[mi][r], off));
          float nm = fmaxf(m[mi][r], pm[mi][r]);
          fr[mi][r] = __expf(m[mi][r] - nm);
          m[mi][r] = nm;
        }
        float rs[4] = {0.f, 0.f, 0.f, 0.f};
        #pragma unroll
        for (int ni = 0; ni < 4; ++ni)
          #pragma unroll
          for (int r = 0; r < 4; ++r) {
            float pe = __expf(pvv[mi][ni][r] - m[mi][r]);
            pvv[mi][ni][r] = pe; rs[r] += pe;
          }
        #pragma unroll
        for (int r = 0; r < 4; ++r) {
          #pragma unroll
          for (int off = 1; off < 16; off <<= 1) rs[r] += __shfl_xor(rs[r], off);
          ll[mi][r] = ll[mi][r]*fr[mi][r] + rs[r];
        }
        #pragma unroll
        for (int f = 0; f < 8; ++f) {
          o[mi][f][0] *= fr[mi][0]; o[mi][f][1] *= fr[mi][1];
          o[mi][f][2] *= fr[mi][2]; o[mi][f][3] *= fr[mi][3];
        }
        #pragma unroll
        for (int ni = 0; ni < 4; ++ni)
          #pragma unroll
          for (int r = 0; r < 4; ++r)
            Ps[wid][mi*16 + l8*4 + r][ni*16 + lrow] = f2bf(pvv[mi][ni][r]);
      }
      bf16x8 pf[2][2];
      #pragma unroll
      for (int mi = 0; mi < 2; ++mi) {
        pf[mi][0] = *(const bf16x8*)&Ps[wid][mi*16 + lrow][l8*8];
        pf[mi][1] = *(const bf16x8*)&Ps[wid][mi*16 + lrow][32 + l8*8];
      }
      __builtin_amdgcn_s_setprio(1);
      #pragma unroll
      for (int f = 0; f < 8; ++f) {
        int d = f*16 + lrow;
        bf16x8 v0 = *(const bf16x8*)&Vc[d*64 + ((l8) ^ x7)*8];
        bf16x8 v1 = *(const bf16x8*)&Vc[d*64 + ((4 + l8) ^ x7)*8];
        o[0][f] = __builtin_amdgcn_mfma_f32_16x16x32_bf16(pf[0][0], v0, o[0][f], 0, 0, 0);
        o[0][f] = __builtin_amdgcn_mfma_f32_16x16x32_bf16(pf[0][1], v1, o[0][f], 0, 0, 0);
        o[1][f] = __builtin_amdgcn_mfma_f32_16x16x32_bf16(pf[1][0], v0, o[1][f], 0, 0, 0);
        o[1][f] = __builtin_amdgcn_mfma_f32_16x16x32_bf16(pf[1][1], v1, o[1][f], 0, 0, 0);
      }
      __builtin_amdgcn_s_setprio(0);
      __syncthreads();
      cur ^= 1;
    }
    float invl[2][4];
    #pragma unroll
    for (int mi = 0; mi < 2; ++mi)
      #pragma unroll
      for (int r = 0; r < 4; ++r) invl[mi][r] = 1.0f / ll[mi][r];
    #pragma unroll
    for (int mi = 0; mi < 2; ++mi)
      #pragma unroll
      for (int f = 0; f < 8; ++f)
        #pragma unroll
        for (int r = 0; r < 4; ++r) {
          long row = (long)b*SEQ + q0 + mi*16 + l8*4 + r;
          ao[row*HID + h*HDIM + f*16 + lrow] = o[mi][f][r] * invl[mi][r];
        }
    __syncthreads();
  }
}

// ---------------- fused rmsnorm + act quant -> int8 ----------------
__global__ __launch_bounds__(256) void k_rmsq8(const float* __restrict__ x, const float* __restrict__ w,
                                               char* __restrict__ yq, float* __restrict__ ys) {
  long row = blockIdx.x;
  const float4* xr = (const float4*)(x + row*HID);
  const float4* wr = (const float4*)w;
  float4 v[4];
  float ss = 0.f;
  #pragma unroll
  for (int j = 0; j < 4; ++j) {
    v[j] = xr[j*256 + threadIdx.x];
    ss += v[j].x*v[j].x + v[j].y*v[j].y + v[j].z*v[j].z + v[j].w*v[j].w;
  }
  #pragma unroll
  for (int off = 1; off < 64; off <<= 1) ss += __shfl_xor(ss, off);
  __shared__ float red[4];
  if ((threadIdx.x & 63) == 0) red[threadIdx.x >> 6] = ss;
  __syncthreads();
  ss = red[0] + red[1] + red[2] + red[3];
  __syncthreads();
  float rn = rsqrtf(ss / (float)HID + 1e-6f);
  float4 y[4];
  float am = 0.f;
  #pragma unroll
  for (int j = 0; j < 4; ++j) {
    float4 wv = wr[j*256 + threadIdx.x];
    y[j].x = v[j].x * rn * wv.x; y[j].y = v[j].y * rn * wv.y;
    y[j].z = v[j].z * rn * wv.z; y[j].w = v[j].w * rn * wv.w;
    am = fmaxf(am, fmaxf(fmaxf(fabsf(y[j].x), fabsf(y[j].y)), fmaxf(fabsf(y[j].z), fabsf(y[j].w))));
  }
  #pragma unroll
  for (int off = 1; off < 64; off <<= 1) am = fmaxf(am, __shfl_xor(am, off));
  if ((threadIdx.x & 63) == 0) red[threadIdx.x >> 6] = am;
  __syncthreads();
  am = fmaxf(fmaxf(red[0], red[1]), fmaxf(red[2], red[3]));
  float amc = fmaxf(am, 1e-5f);
  float s = 127.0f / amc;
  int* oq = (int*)(yq + row*HID);
  #pragma unroll
  for (int j = 0; j < 4; ++j)
    oq[j*256 + threadIdx.x] = pack4i8(y[j].x, y[j].y, y[j].z, y[j].w, s, -128.f, 127.f);
  if (threadIdx.x == 0) ys[row] = amc / 127.0f;
}

extern "C" void kernel_launch(void* const* d_in, const int* in_sizes, int n_in,
                              void* d_out, int out_size, void* d_ws, size_t ws_size,
                              hipStream_t stream) {
  const float* hs    = (const float*)d_in[0];
  const float* w_q   = (const float*)d_in[2];
  const float* w_k   = (const float*)d_in[3];
  const float* w_v   = (const float*)d_in[4];
  const float* w_o   = (const float*)d_in[5];
  const float* subln = (const float*)d_in[6];

  char* ws = (char*)d_ws;
  char*  wqq = (char*)(ws + 0L);                  // 16777216 (i8, rows perm'd)
  char*  wqk = (char*)(ws + 16777216L);           // 4194304  (i8, rows perm'd)
  char*  wqv = (char*)(ws + 20971520L);           // 4194304
  char*  wqo = (char*)(ws + 25165824L);           // 16777216
  char*  xq  = (char*)(ws + 41943040L);           // 8388608
  float* ao  = (float*)(ws + 50331648L);          // 33554432 (fp32 attention out)
  char*  yq  = (char*)(ws + 83886080L);           // 8388608  (i8 rmsnorm out)
  u16*   qb  = (u16*)(ws + 92274688L);            // 16777216 (bf16 rope'd Q)
  u16*   kb  = (u16*)(ws + 109051904L);           // 4194304  (bf16 rope'd K)
  u16*   vtb = (u16*)(ws + 113246208L);           // 4194304  (bf16 V^T)
  float* cosb= (float*)(ws + 117440512L);         // 262144
  float* sinb= (float*)(ws + 117702656L);         // 262144
  float* xs  = (float*)(ws + 117964800L);         // 8192
  float* ys  = (float*)(ws + 117972992L);         // 8192
  float* wsc = (float*)(ws + 117981184L);         // 64
  float* par = (float*)(ws + 117981248L);         // 16384
  float* out = (float*)d_out;

  // 1. pass 1 merged: weight abs-sums + act quant
  k_pass1<<<4608, 256, 0, stream>>>(w_q, w_k, w_v, w_o, par, hs, xq, xs);
  k_wscale<<<1, 256, 0, stream>>>(par, wsc);

  // 2. quantize weights (merged with rope tables)
  k_quantw8_all<<<41216, 256, 0, stream>>>(w_q, w_k, w_v, w_o, wqq, wqk, wqv, wqo, wsc, cosb, sinb);

  // 3. merged Q/K/V i8 GEMM (2-wave, single-barrier, uniform gload_lds pipeline)
  k_gemm8_qkv<<<768, 128, 0, stream>>>(xq, wqq, wqk, wqv, qb, kb, vtb, xs, wsc, cosb, sinb);

  // 4. attention (2 waves x 32 q-rows, K+V LDS dbuf, causal-paired)
  k_attn<<<dim3(8, 32, 2), 128, 0, stream>>>(qb, kb, vtb, ao);

  // 5. rmsnorm + act quant
  k_rmsq8<<<NROWS, 256, 0, stream>>>(ao, subln, yq, ys);

  // 6. output i8 GEMM (2-wave, single-barrier, uniform gload_lds pipeline)
  k_gemm8<<<512, 128, 0, stream>>>(yq, wqo, out, ys, wsc, 3, NROWS, 4096, 4096);
}

// Round 13
// 239.419 us; speedup vs baseline: 1.1477x; 1.1477x over previous
//
#include <hip/hip_runtime.h>
#include <hip/hip_bf16.h>
#include <cstdint>

typedef unsigned short u16;
typedef __bf16 bf16x8 __attribute__((ext_vector_type(8)));
typedef float f32x4 __attribute__((ext_vector_type(4)));
typedef int i32x4 __attribute__((ext_vector_type(4)));

#define SEQ 1024
#define HID 4096
#define NHQ 32
#define NKVH 8
#define HDIM 128
#define NB 2
#define NROWS (NB*SEQ)

static __device__ __forceinline__ u16 f2bf(float x) {
  __hip_bfloat16 h = __float2bfloat16(x);
  return *reinterpret_cast<u16*>(&h);
}

static __device__ __forceinline__ void gload16(const void* g, void* l) {
  __builtin_amdgcn_global_load_lds((__attribute__((address_space(1))) void*)(void*)g,
                                   (__attribute__((address_space(3))) void*)l, 16, 0, 0);
}

static __device__ __forceinline__ int pack4i8(float a, float b, float c, float d,
                                              float s, float lo, float hi) {
  int x0 = (int)fminf(fmaxf(rintf(a*s), lo), hi);
  int x1 = (int)fminf(fmaxf(rintf(b*s), lo), hi);
  int x2 = (int)fminf(fmaxf(rintf(c*s), lo), hi);
  int x3 = (int)fminf(fmaxf(rintf(d*s), lo), hi);
  return (x0 & 255) | ((x1 & 255) << 8) | ((x2 & 255) << 16) | ((x3 & 255) << 24);
}

// ---------------- pass 1 (merged): weight abs-sums (bx<2560) + act quant (bx>=2560) ----------------
__global__ __launch_bounds__(256) void k_pass1(const float* __restrict__ wq_, const float* __restrict__ wk_,
                                               const float* __restrict__ wv_, const float* __restrict__ wo_,
                                               float* __restrict__ partial,
                                               const float* __restrict__ x, char* __restrict__ xq,
                                               float* __restrict__ xs) {
  __shared__ float red[4];
  int bx = blockIdx.x;
  if (bx < 2560) {
    const float* w; long n4; int pbase, lb, nb;
    if (bx < 1024)      { w = wq_; n4 = 4194304; pbase = 0;    lb = bx;        nb = 1024; }
    else if (bx < 1280) { w = wk_; n4 = 1048576; pbase = 1024; lb = bx - 1024; nb = 256; }
    else if (bx < 1536) { w = wv_; n4 = 1048576; pbase = 1280; lb = bx - 1280; nb = 256; }
    else                { w = wo_; n4 = 4194304; pbase = 1536; lb = bx - 1536; nb = 1024; }
    float s = 0.f;
    long stride = (long)nb * 256;
    const float4* w4 = (const float4*)w;
    for (long j = (long)lb*256 + threadIdx.x; j < n4; j += stride) {
      float4 v = w4[j];
      s += fabsf(v.x) + fabsf(v.y) + fabsf(v.z) + fabsf(v.w);
    }
    #pragma unroll
    for (int off = 1; off < 64; off <<= 1) s += __shfl_xor(s, off);
    if ((threadIdx.x & 63) == 0) red[threadIdx.x >> 6] = s;
    __syncthreads();
    if (threadIdx.x == 0) partial[pbase + lb] = red[0] + red[1] + red[2] + red[3];
  } else {
    long row = bx - 2560;
    const float4* xr = (const float4*)(x + row*HID);
    float4 v[4];
    float am = 0.f;
    #pragma unroll
    for (int j = 0; j < 4; ++j) {
      v[j] = xr[j*256 + threadIdx.x];
      am = fmaxf(am, fmaxf(fmaxf(fabsf(v[j].x), fabsf(v[j].y)), fmaxf(fabsf(v[j].z), fabsf(v[j].w))));
    }
    #pragma unroll
    for (int off = 1; off < 64; off <<= 1) am = fmaxf(am, __shfl_xor(am, off));
    if ((threadIdx.x & 63) == 0) red[threadIdx.x >> 6] = am;
    __syncthreads();
    am = fmaxf(fmaxf(red[0], red[1]), fmaxf(red[2], red[3]));
    float amc = fmaxf(am, 1e-5f);
    float s = 127.0f / amc;
    int* oq = (int*)(xq + row*HID);
    #pragma unroll
    for (int j = 0; j < 4; ++j)
      oq[j*256 + threadIdx.x] = pack4i8(v[j].x, v[j].y, v[j].z, v[j].w, s, -128.f, 127.f);
    if (threadIdx.x == 0) xs[row] = amc / 127.0f;
  }
}

// ---------------- weight scales (pass 2) ----------------
__global__ __launch_bounds__(256) void k_wscale(const float* __restrict__ partial,
                                                float* __restrict__ wsc) {
  __shared__ float red[4];
  const float nelem[4] = {16777216.f, 4194304.f, 4194304.f, 16777216.f};
  const int pbase[4] = {0, 1024, 1280, 1536};
  const int pcnt[4]  = {1024, 256, 256, 1024};
  for (int wi = 0; wi < 4; ++wi) {
    float s = 0.f;
    for (int j = threadIdx.x; j < pcnt[wi]; j += 256) s += partial[pbase[wi] + j];
    #pragma unroll
    for (int off = 1; off < 64; off <<= 1) s += __shfl_xor(s, off);
    if ((threadIdx.x & 63) == 0) red[threadIdx.x >> 6] = s;
    __syncthreads();
    if (threadIdx.x == 0) wsc[wi] = fmaxf((red[0]+red[1]+red[2]+red[3]) / nelem[wi], 1e-5f);
    __syncthreads();
  }
}

// ---------------- merged ternary weight quantize -> int8 + rope tables (41216 blocks) ----------------
__global__ __launch_bounds__(256) void k_quantw8_all(const float* __restrict__ wq_, const float* __restrict__ wk_,
                                                     const float* __restrict__ wv_, const float* __restrict__ wo_,
                                                     char* __restrict__ oq_, char* __restrict__ ok_,
                                                     char* __restrict__ ov_, char* __restrict__ oo_,
                                                     const float* __restrict__ wsc,
                                                     float* __restrict__ cosb, float* __restrict__ sinb) {
  int bx = blockIdx.x;
  if (bx >= 40960) {
    int idx = (bx - 40960)*256 + threadIdx.x;     // 1024*64
    int s = idx >> 6, i = idx & 63;
    float e = (2.0f * (float)i) / 128.0f;
    float inv = 1.0f / powf(500000.0f, e);
    float f = (float)s * inv;
    cosb[idx] = cosf(f);
    sinb[idx] = sinf(f);
    return;
  }
  const float* src; char* dst; int idx; long base;
  if (bx < 16384)      { src = wq_; dst = oq_; idx = 0; base = bx; }
  else if (bx < 20480) { src = wk_; dst = ok_; idx = 1; base = bx - 16384; }
  else if (bx < 24576) { src = wv_; dst = ov_; idx = 2; base = bx - 20480; }
  else                 { src = wo_; dst = oo_; idx = 3; base = bx - 24576; }
  long j = base*256 + threadIdx.x;        // float4 index; 1024 per weight row
  long oj = j;
  if (idx <= 1) {
    long row = j >> 10;
    int u = (int)(row & 31);
    long prow = (row & ~31L) | (long)((u >> 1) | ((u & 1) << 4));
    oj = (prow << 10) | (j & 1023);
  }
  float inv = 1.0f / wsc[idx];
  float4 v = ((const float4*)src)[j];
  ((int*)dst)[oj] = pack4i8(v.x, v.y, v.z, v.w, inv, -1.f, 1.f);
}

// ---------------- i8 O-GEMM: 128x128 tile, 2 waves (64x128 each), 1 barrier/step ----------------
// Counted-vmcnt pipeline over a UNIFORM global_load_lds stream (FIFO-safe, m135/m218).
__global__ __launch_bounds__(128, 2) void k_gemm8(const char* __restrict__ A, const char* __restrict__ W,
                                                  float* __restrict__ C, const float* __restrict__ arow,
                                                  const float* __restrict__ wsc, int widx,
                                                  int M, int N, int K) {
  __shared__ char As[3][128*64] __attribute__((aligned(16)));
  __shared__ char Ws_[3][128*64] __attribute__((aligned(16)));
  int t = threadIdx.x;
  int bid = blockIdx.x;
  int xcd = bid & 7, w = bid >> 3;                 // w in 0..63
  int bm = ((xcd & 1) << 3) + (w >> 3);            // 0..15
  int bn = ((xcd >> 1) << 3) + (w & 7);            // 0..31
  const char* Ab = A + (long)bm*128*K;
  const char* Wb = W + (long)bn*128*K;
  int lane = t & 63, wid = t >> 6;
  int lrow = lane & 15, l8 = lane >> 4;
  int ch0 = (l8 ^ ((lrow >> 1) & 3)) * 16;
  i32x4 zero = {0, 0, 0, 0};
  i32x4 acc[4][8];
  #pragma unroll
  for (int mi = 0; mi < 4; ++mi)
    #pragma unroll
    for (int ni = 0; ni < 8; ++ni) acc[mi][ni] = zero;

  auto stage = [&](int buf, int kt) {              // 8 VMEM ops per thread (all gload_lds)
    #pragma unroll
    for (int i = 0; i < 4; ++i) {
      int c = t + 128*i;
      int row = c >> 2;
      int ci = ((c & 3) ^ ((row >> 1) & 3)) * 16;  // pre-swizzled global chunk (rule #21)
      gload16(Ab + (long)row*K + kt*64 + ci, &As[buf][c*16]);
      gload16(Wb + (long)row*K + kt*64 + ci, &Ws_[buf][c*16]);
    }
  };

  int nk = K >> 6;                                 // 64
  stage(0, 0); stage(1, 1);
  asm volatile("s_waitcnt vmcnt(8)" ::: "memory");
  __builtin_amdgcn_sched_barrier(0);
  __builtin_amdgcn_s_barrier();
  __builtin_amdgcn_sched_barrier(0);
  for (int kt = 0; kt < nk; ++kt) {
    int cur = kt % 3;
    i32x4 af[4], bfr[8];
    #pragma unroll
    for (int mi = 0; mi < 4; ++mi) af[mi] = *(const i32x4*)&As[cur][(wid*64 + mi*16 + lrow)*64 + ch0];
    #pragma unroll
    for (int ni = 0; ni < 8; ++ni) bfr[ni] = *(const i32x4*)&Ws_[cur][(ni*16 + lrow)*64 + ch0];
    if (kt + 2 < nk) stage((kt + 2) % 3, kt + 2);
    __builtin_amdgcn_s_setprio(1);
    #pragma unroll
    for (int mi = 0; mi < 4; ++mi)
      #pragma unroll
      for (int ni = 0; ni < 8; ++ni)
        acc[mi][ni] = __builtin_amdgcn_mfma_i32_16x16x64_i8(af[mi], bfr[ni], acc[mi][ni], 0, 0, 0);
    __builtin_amdgcn_s_setprio(0);
    if (kt + 2 < nk)      asm volatile("s_waitcnt vmcnt(8)" ::: "memory");
    else if (kt + 1 < nk) asm volatile("s_waitcnt vmcnt(0)" ::: "memory");
    if (kt + 1 < nk) {
      __builtin_amdgcn_sched_barrier(0);
      __builtin_amdgcn_s_barrier();
      __builtin_amdgcn_sched_barrier(0);
    }
  }
  float ws = wsc[widx];
  #pragma unroll
  for (int mi = 0; mi < 4; ++mi)
    #pragma unroll
    for (int r = 0; r < 4; ++r) {
      int row = bm*128 + wid*64 + mi*16 + l8*4 + r;
      float sc = arow[row] * ws;
      #pragma unroll
      for (int ni = 0; ni < 8; ++ni) {
        int col = bn*128 + ni*16 + lrow;
        C[(long)row*N + col] = (float)acc[mi][ni][r] * sc;
      }
    }
}

// ---------------- merged i8 QKV GEMM: 128x128, 2 waves, 1 barrier/step, fused RoPE ----------------
__global__ __launch_bounds__(128, 2) void k_gemm8_qkv(const char* __restrict__ A,
    const char* __restrict__ Wq, const char* __restrict__ Wk, const char* __restrict__ Wv,
    u16* __restrict__ Qb, u16* __restrict__ Kb, u16* __restrict__ Vt,
    const float* __restrict__ arow, const float* __restrict__ wsc,
    const float* __restrict__ cosb, const float* __restrict__ sinb) {
  const int K = 4096;
  int bid = blockIdx.x;
  int xcd = bid & 7, w = bid >> 3;                 // w in 0..95
  int kind, bm, bn;
  const char* W;
  if (w < 64)      { kind = 0; bm = ((xcd & 1) << 3) + (w >> 3); bn = ((xcd >> 1) << 3) + (w & 7); W = Wq; }
  else if (w < 80) { int u = w - 64; kind = 1; bm = (xcd << 1) + (u >> 3); bn = u & 7; W = Wk; }
  else             { int u = w - 80; kind = 2; bm = (xcd << 1) + (u >> 3); bn = u & 7; W = Wv; }

  __shared__ char As[3][128*64] __attribute__((aligned(16)));
  __shared__ char Ws_[3][128*64] __attribute__((aligned(16)));
  int t = threadIdx.x;
  const char* Ab = A + (long)bm*128*K;
  const char* Wb = W + (long)bn*128*K;
  int lane = t & 63, wid = t >> 6;
  int lrow = lane & 15, l8 = lane >> 4;
  int ch0 = (l8 ^ ((lrow >> 1) & 3)) * 16;
  i32x4 zero = {0, 0, 0, 0};
  i32x4 acc[4][8];
  #pragma unroll
  for (int mi = 0; mi < 4; ++mi)
    #pragma unroll
    for (int ni = 0; ni < 8; ++ni) acc[mi][ni] = zero;

  auto stage = [&](int buf, int kt) {              // 8 VMEM ops per thread (all gload_lds)
    #pragma unroll
    for (int i = 0; i < 4; ++i) {
      int c = t + 128*i;
      int row = c >> 2;
      int ci = ((c & 3) ^ ((row >> 1) & 3)) * 16;
      gload16(Ab + (long)row*K + kt*64 + ci, &As[buf][c*16]);
      gload16(Wb + (long)row*K + kt*64 + ci, &Ws_[buf][c*16]);
    }
  };

  int nk = K >> 6;                                 // 64
  stage(0, 0); stage(1, 1);
  asm volatile("s_waitcnt vmcnt(8)" ::: "memory");
  __builtin_amdgcn_sched_barrier(0);
  __builtin_amdgcn_s_barrier();
  __builtin_amdgcn_sched_barrier(0);
  for (int kt = 0; kt < nk; ++kt) {
    int cur = kt % 3;
    i32x4 af[4], bfr[8];
    #pragma unroll
    for (int mi = 0; mi < 4; ++mi) af[mi] = *(const i32x4*)&As[cur][(wid*64 + mi*16 + lrow)*64 + ch0];
    #pragma unroll
    for (int ni = 0; ni < 8; ++ni) bfr[ni] = *(const i32x4*)&Ws_[cur][(ni*16 + lrow)*64 + ch0];
    if (kt + 2 < nk) stage((kt + 2) % 3, kt + 2);
    __builtin_amdgcn_s_setprio(1);
    #pragma unroll
    for (int mi = 0; mi < 4; ++mi)
      #pragma unroll
      for (int ni = 0; ni < 8; ++ni)
        acc[mi][ni] = __builtin_amdgcn_mfma_i32_16x16x64_i8(af[mi], bfr[ni], acc[mi][ni], 0, 0, 0);
    __builtin_amdgcn_s_setprio(0);
    if (kt + 2 < nk)      asm volatile("s_waitcnt vmcnt(8)" ::: "memory");
    else if (kt + 1 < nk) asm volatile("s_waitcnt vmcnt(0)" ::: "memory");
    if (kt + 1 < nk) {
      __builtin_amdgcn_sched_barrier(0);
      __builtin_amdgcn_s_barrier();
      __builtin_amdgcn_sched_barrier(0);
    }
  }

  if (kind == 2) {
    float ws = wsc[2];
    #pragma unroll
    for (int mi = 0; mi < 4; ++mi) {
      int row0 = bm*128 + wid*64 + mi*16 + l8*4;
      int bidx = row0 >> 10, s0 = row0 & 1023;
      #pragma unroll
      for (int ni = 0; ni < 8; ++ni) {
        int col = bn*128 + ni*16 + lrow;
        int hkv = col >> 7, d = col & 127;
        ushort4 o4;
        o4.x = f2bf((float)acc[mi][ni][0] * arow[row0+0] * ws);
        o4.y = f2bf((float)acc[mi][ni][1] * arow[row0+1] * ws);
        o4.z = f2bf((float)acc[mi][ni][2] * arow[row0+2] * ws);
        o4.w = f2bf((float)acc[mi][ni][3] * arow[row0+3] * ws);
        *(ushort4*)&Vt[(((long)bidx*NKVH + hkv)*HDIM + d)*SEQ + s0] = o4;
      }
    }
  } else {
    // Weight rows permuted at quant: (acc[mi][2j], acc[mi][2j+1]) are the RoPE pair
    // (B+2*lrow, B+2*lrow+1), B = bn*128 + j*32 — lane-local, no shfl.
    float ws = wsc[kind];
    u16* dst = kind ? Kb : Qb;
    int nh = kind ? NKVH : NHQ;
    #pragma unroll
    for (int mi = 0; mi < 4; ++mi) {
      #pragma unroll
      for (int r = 0; r < 4; ++r) {
        int row = bm*128 + wid*64 + mi*16 + l8*4 + r;
        int bidx = row >> 10, s = row & 1023;
        float sc = arow[row] * ws;
        #pragma unroll
        for (int j = 0; j < 4; ++j) {
          float a  = (float)acc[mi][2*j][r] * sc;
          float b2 = (float)acc[mi][2*j+1][r] * sc;
          int B = bn*128 + j*32;
          int h = B >> 7;
          int d = (B & 127) + 2*lrow;
          int i = d >> 1;
          float cc = cosb[(s << 6) + i], sn = sinb[(s << 6) + i];
          ushort2 o2;
          o2.x = f2bf(a*cc - b2*sn);
          o2.y = f2bf(a*sn + b2*cc);
          *(ushort2*)&dst[(((long)bidx*nh + h)*SEQ + s)*HDIM + d] = o2;
        }
      }
    }
  }
}

// ---------------- causal GQA flash attention, K+V LDS-staged (dbuf), 4 waves x 16 rows, causal-paired ----------------
__global__ __launch_bounds__(256) void k_attn(const u16* __restrict__ qb, const u16* __restrict__ kb,
                                              const u16* __restrict__ vt, float* __restrict__ ao) {
  int p = blockIdx.x, h = blockIdx.y, b = blockIdx.z;
  int t = threadIdx.x, lane = t & 63, wid = t >> 6;
  int lrow = lane & 15, l8 = lane >> 4;
  int x7 = lrow & 7;

  __shared__ u16 Ks[2][64*128] __attribute__((aligned(16)));
  __shared__ u16 Vs[2][128*64] __attribute__((aligned(16)));
  __shared__ u16 Ps[4][16][72] __attribute__((aligned(16)));

  const u16* kp = kb + ((long)(b*NKVH + (h >> 2)))*SEQ*HDIM;
  const u16* vp = vt + ((long)(b*NKVH + (h >> 2)))*HDIM*SEQ;

  auto stageK = [&](int buf, int j) {
    const u16* src = kp + (long)j*64*HDIM;
    #pragma unroll
    for (int i = 0; i < 4; ++i) {
      int r0 = wid*16 + i*4;
      int row = r0 + (lane >> 4);
      int cg = (lane & 15) ^ (row & 7);
      gload16(src + (long)row*HDIM + cg*8, &Ks[buf][r0*HDIM]);
    }
  };
  auto stageV = [&](int buf, int j) {
    #pragma unroll
    for (int i = 0; i < 4; ++i) {
      int r0 = wid*32 + i*8;
      int row = r0 + (lane >> 3);
      int cg = (lane & 7) ^ (row & 7);
      gload16(vp + (long)row*SEQ + j*64 + cg*8, &Vs[buf][r0*64]);
    }
  };

  for (int phase = 0; phase < 2; ++phase) {
    int qt = phase ? (15 - p) : p;
    int q0 = qt*64 + wid*16;
    const u16* qp = qb + (((long)(b*NHQ + h))*SEQ + q0)*HDIM;
    bf16x8 qf[4];
    #pragma unroll
    for (int ks = 0; ks < 4; ++ks) qf[ks] = *(const bf16x8*)&qp[lrow*HDIM + ks*32 + l8*8];
    f32x4 zero = {0.f, 0.f, 0.f, 0.f};
    f32x4 o[8];
    #pragma unroll
    for (int f = 0; f < 8; ++f) o[f] = zero;
    float m[4], ll[4];
    #pragma unroll
    for (int r = 0; r < 4; ++r) { m[r] = -1e30f; ll[r] = 0.f; }

    int nj = qt + 1;
    stageK(0, 0); stageV(0, 0);
    __syncthreads();
    int cur = 0;
    for (int j = 0; j < nj; ++j) {
      if (j + 1 < nj) { stageK(cur ^ 1, j + 1); stageV(cur ^ 1, j + 1); }
      const u16* Kc = Ks[cur];
      const u16* Vc = Vs[cur];
      f32x4 sc4[4];
      #pragma unroll
      for (int ni = 0; ni < 4; ++ni) sc4[ni] = zero;
      __builtin_amdgcn_s_setprio(1);
      #pragma unroll
      for (int ni = 0; ni < 4; ++ni) {
        int row = ni*16 + lrow;
        #pragma unroll
        for (int ks = 0; ks < 4; ++ks) {
          int cl = (ks*4 + l8) ^ x7;
          bf16x8 kfr = *(const bf16x8*)&Kc[row*HDIM + cl*8];
          sc4[ni] = __builtin_amdgcn_mfma_f32_16x16x32_bf16(qf[ks], kfr, sc4[ni], 0, 0, 0);
        }
      }
      __builtin_amdgcn_s_setprio(0);
      const float scale = 0.08838834764831845f;
      float pm[4] = {-1e30f, -1e30f, -1e30f, -1e30f};
      float pv[4][4];
      bool diag = (j == qt);
      #pragma unroll
      for (int ni = 0; ni < 4; ++ni) {
        int kv = j*64 + ni*16 + lrow;
        #pragma unroll
        for (int r = 0; r < 4; ++r) {
          int qr = q0 + l8*4 + r;
          float val = sc4[ni][r] * scale;
          if (diag && kv > qr) val = -1e30f;
          pv[ni][r] = val;
          pm[r] = fmaxf(pm[r], val);
        }
      }
      #pragma unroll
      for (int r = 0; r < 4; ++r) {
        #pragma unroll
        for (int off = 1; off < 16; off <<= 1) pm[r] = fmaxf(pm[r], __shfl_xor(pm[r], off));
      }
      float fr[4], rs[4];
      #pragma unroll
      for (int r = 0; r < 4; ++r) {
        float nm = fmaxf(m[r], pm[r]);
        fr[r] = __expf(m[r] - nm);
        m[r] = nm; rs[r] = 0.f;
      }
      #pragma unroll
      for (int ni = 0; ni < 4; ++ni)
        #pragma unroll
        for (int r = 0; r < 4; ++r) {
          float pe = __expf(pv[ni][r] - m[r]);
          pv[ni][r] = pe; rs[r] += pe;
        }
      #pragma unroll
      for (int r = 0; r < 4; ++r) {
        #pragma unroll
        for (int off = 1; off < 16; off <<= 1) rs[r] += __shfl_xor(rs[r], off);
        ll[r] = ll[r]*fr[r] + rs[r];
      }
      #pragma unroll
      for (int f = 0; f < 8; ++f) {
        o[f][0] *= fr[0]; o[f][1] *= fr[1]; o[f][2] *= fr[2]; o[f][3] *= fr[3];
      }
      #pragma unroll
      for (int ni = 0; ni < 4; ++ni)
        #pragma unroll
        for (int r = 0; r < 4; ++r)
          Ps[wid][l8*4 + r][ni*16 + lrow] = f2bf(pv[ni][r]);
      bf16x8 pf0 = *(const bf16x8*)&Ps[wid][lrow][l8*8];
      bf16x8 pf1 = *(const bf16x8*)&Ps[wid][lrow][32 + l8*8];
      __builtin_amdgcn_s_setprio(1);
      #pragma unroll
      for (int f = 0; f < 8; ++f) {
        int d = f*16 + lrow;
        bf16x8 v0 = *(const bf16x8*)&Vc[d*64 + ((l8) ^ x7)*8];
        bf16x8 v1 = *(const bf16x8*)&Vc[d*64 + ((4 + l8) ^ x7)*8];
        o[f] = __builtin_amdgcn_mfma_f32_16x16x32_bf16(pf0, v0, o[f], 0, 0, 0);
        o[f] = __builtin_amdgcn_mfma_f32_16x16x32_bf16(pf1, v1, o[f], 0, 0, 0);
      }
      __builtin_amdgcn_s_setprio(0);
      __syncthreads();
      cur ^= 1;
    }
    float invl[4];
    #pragma unroll
    for (int r = 0; r < 4; ++r) invl[r] = 1.0f / ll[r];
    #pragma unroll
    for (int f = 0; f < 8; ++f)
      #pragma unroll
      for (int r = 0; r < 4; ++r) {
        long row = (long)b*SEQ + q0 + l8*4 + r;
        ao[row*HID + h*HDIM + f*16 + lrow] = o[f][r] * invl[r];
      }
    __syncthreads();
  }
}

// ---------------- fused rmsnorm + act quant -> int8 ----------------
__global__ __launch_bounds__(256) void k_rmsq8(const float* __restrict__ x, const float* __restrict__ w,
                                               char* __restrict__ yq, float* __restrict__ ys) {
  long row = blockIdx.x;
  const float4* xr = (const float4*)(x + row*HID);
  const float4* wr = (const float4*)w;
  float4 v[4];
  float ss = 0.f;
  #pragma unroll
  for (int j = 0; j < 4; ++j) {
    v[j] = xr[j*256 + threadIdx.x];
    ss += v[j].x*v[j].x + v[j].y*v[j].y + v[j].z*v[j].z + v[j].w*v[j].w;
  }
  #pragma unroll
  for (int off = 1; off < 64; off <<= 1) ss += __shfl_xor(ss, off);
  __shared__ float red[4];
  if ((threadIdx.x & 63) == 0) red[threadIdx.x >> 6] = ss;
  __syncthreads();
  ss = red[0] + red[1] + red[2] + red[3];
  __syncthreads();
  float rn = rsqrtf(ss / (float)HID + 1e-6f);
  float4 y[4];
  float am = 0.f;
  #pragma unroll
  for (int j = 0; j < 4; ++j) {
    float4 wv = wr[j*256 + threadIdx.x];
    y[j].x = v[j].x * rn * wv.x; y[j].y = v[j].y * rn * wv.y;
    y[j].z = v[j].z * rn * wv.z; y[j].w = v[j].w * rn * wv.w;
    am = fmaxf(am, fmaxf(fmaxf(fabsf(y[j].x), fabsf(y[j].y)), fmaxf(fabsf(y[j].z), fabsf(y[j].w))));
  }
  #pragma unroll
  for (int off = 1; off < 64; off <<= 1) am = fmaxf(am, __shfl_xor(am, off));
  if ((threadIdx.x & 63) == 0) red[threadIdx.x >> 6] = am;
  __syncthreads();
  am = fmaxf(fmaxf(red[0], red[1]), fmaxf(red[2], red[3]));
  float amc = fmaxf(am, 1e-5f);
  float s = 127.0f / amc;
  int* oq = (int*)(yq + row*HID);
  #pragma unroll
  for (int j = 0; j < 4; ++j)
    oq[j*256 + threadIdx.x] = pack4i8(y[j].x, y[j].y, y[j].z, y[j].w, s, -128.f, 127.f);
  if (threadIdx.x == 0) ys[row] = amc / 127.0f;
}

extern "C" void kernel_launch(void* const* d_in, const int* in_sizes, int n_in,
                              void* d_out, int out_size, void* d_ws, size_t ws_size,
                              hipStream_t stream) {
  const float* hs    = (const float*)d_in[0];
  const float* w_q   = (const float*)d_in[2];
  const float* w_k   = (const float*)d_in[3];
  const float* w_v   = (const float*)d_in[4];
  const float* w_o   = (const float*)d_in[5];
  const float* subln = (const float*)d_in[6];

  char* ws = (char*)d_ws;
  char*  wqq = (char*)(ws + 0L);                  // 16777216 (i8, rows perm'd)
  char*  wqk = (char*)(ws + 16777216L);           // 4194304  (i8, rows perm'd)
  char*  wqv = (char*)(ws + 20971520L);           // 4194304
  char*  wqo = (char*)(ws + 25165824L);           // 16777216
  char*  xq  = (char*)(ws + 41943040L);           // 8388608
  float* ao  = (float*)(ws + 50331648L);          // 33554432 (fp32 attention out)
  char*  yq  = (char*)(ws + 83886080L);           // 8388608  (i8 rmsnorm out)
  u16*   qb  = (u16*)(ws + 92274688L);            // 16777216 (bf16 rope'd Q)
  u16*   kb  = (u16*)(ws + 109051904L);           // 4194304  (bf16 rope'd K)
  u16*   vtb = (u16*)(ws + 113246208L);           // 4194304  (bf16 V^T)
  float* cosb= (float*)(ws + 117440512L);         // 262144
  float* sinb= (float*)(ws + 117702656L);         // 262144
  float* xs  = (float*)(ws + 117964800L);         // 8192
  float* ys  = (float*)(ws + 117972992L);         // 8192
  float* wsc = (float*)(ws + 117981184L);         // 64
  float* par = (float*)(ws + 117981248L);         // 16384
  float* out = (float*)d_out;

  // 1. pass 1 merged: weight abs-sums + act quant
  k_pass1<<<4608, 256, 0, stream>>>(w_q, w_k, w_v, w_o, par, hs, xq, xs);
  k_wscale<<<1, 256, 0, stream>>>(par, wsc);

  // 2. quantize weights (merged with rope tables)
  k_quantw8_all<<<41216, 256, 0, stream>>>(w_q, w_k, w_v, w_o, wqq, wqk, wqv, wqo, wsc, cosb, sinb);

  // 3. merged Q/K/V i8 GEMM (2-wave, single-barrier, uniform gload_lds pipeline)
  k_gemm8_qkv<<<768, 128, 0, stream>>>(xq, wqq, wqk, wqv, qb, kb, vtb, xs, wsc, cosb, sinb);

  // 4. attention (4 waves x 16 q-rows, K+V LDS dbuf, causal-paired)
  k_attn<<<dim3(8, 32, 2), 256, 0, stream>>>(qb, kb, vtb, ao);

  // 5. rmsnorm + act quant
  k_rmsq8<<<NROWS, 256, 0, stream>>>(ao, subln, yq, ys);

  // 6. output i8 GEMM (2-wave, single-barrier, uniform gload_lds pipeline)
  k_gemm8<<<512, 128, 0, stream>>>(yq, wqo, out, ys, wsc, 3, NROWS, 4096, 4096);
}